// Round 1
// baseline (891.793 us; speedup 1.0000x reference)
//
#include <hip/hip_runtime.h>

#define N_NODES   50000
#define N_EDGES   1600000
#define CH        128
#define OUTC      2
#define NGRAPHS   64

// ---------------- CSR build ----------------

__global__ void count_k(const int* __restrict__ dst, int* __restrict__ cnt) {
    int e = blockIdx.x * 256 + threadIdx.x;
    if (e < N_EDGES) atomicAdd(&cnt[dst[e]], 1);
}

// single-block exclusive scan over cnt[N_NODES]; also dis = rsqrt(cnt+1), cursor = offsets
__global__ __launch_bounds__(1024) void scan_k(const int* __restrict__ cnt,
                                               int* __restrict__ offsets,
                                               int* __restrict__ cursor,
                                               float* __restrict__ dis) {
    __shared__ int wsum[16];
    __shared__ int wpre[16];
    __shared__ int btot;
    const int tid  = threadIdx.x;
    const int lane = tid & 63;
    const int wid  = tid >> 6;
    int running = 0;
    for (int base = 0; base < N_NODES; base += 1024) {
        int i = base + tid;
        int c = (i < N_NODES) ? cnt[i] : 0;
        int v = c;
        #pragma unroll
        for (int d = 1; d < 64; d <<= 1) {
            int o = __shfl_up(v, d, 64);
            if (lane >= d) v += o;
        }
        if (lane == 63) wsum[wid] = v;
        __syncthreads();
        if (tid < 16) {
            int s  = wsum[tid];
            int sv = s;
            #pragma unroll
            for (int d = 1; d < 16; d <<= 1) {
                int o = __shfl_up(sv, d, 16);
                if (tid >= d) sv += o;
            }
            wpre[tid] = sv - s;          // exclusive prefix of wave sums
            if (tid == 15) btot = sv;    // chunk total
        }
        __syncthreads();
        int excl = v - c + wpre[wid] + running;
        if (i < N_NODES) {
            offsets[i] = excl;
            cursor[i]  = excl;
            dis[i]     = rsqrtf((float)(c + 1));
        }
        running += btot;
        __syncthreads();   // protect wsum/btot before next chunk
    }
    if (tid == 0) offsets[N_NODES] = running;
}

__global__ void fill_k(const int* __restrict__ src, const int* __restrict__ dst,
                       int* __restrict__ cursor, int* __restrict__ csr) {
    int e = blockIdx.x * 256 + threadIdx.x;
    if (e < N_EDGES) {
        int d = dst[e];
        int pos = atomicAdd(&cursor[d], 1);
        csr[pos] = src[e];
    }
}

// ---------------- GEMM:  out = (h @ W) * dis[row]  ----------------
// 16 rows per block, 256 threads, thread computes 2 rows x 4 cols.
__global__ __launch_bounds__(256) void gemm_scale_k(const float* __restrict__ h,
                                                    const float* __restrict__ W,
                                                    const float* __restrict__ dis,
                                                    float* __restrict__ out) {
    __shared__ float Hl[16 * CH];   // 8 KB
    __shared__ float Wl[64 * CH];   // 32 KB
    const int tid = threadIdx.x;
    const int rowBase = blockIdx.x * 16;

    // load 16 rows of h (512 float4s, 2 per thread)
    #pragma unroll
    for (int i = 0; i < 2; i++) {
        int f   = tid + i * 256;       // 0..511
        int r   = f >> 5;              // 0..15
        int c4  = (f & 31) * 4;
        int n   = rowBase + r;
        float4 v = make_float4(0.f, 0.f, 0.f, 0.f);
        if (n < N_NODES) v = *(const float4*)&h[n * CH + c4];
        *(float4*)&Hl[r * CH + c4] = v;
    }

    const int r  = tid >> 5;          // 0..7  (rows r and r+8)
    const int cg = (tid & 31) * 4;    // col group
    float4 acc0 = make_float4(0.f, 0.f, 0.f, 0.f);
    float4 acc1 = make_float4(0.f, 0.f, 0.f, 0.f);

    for (int kt = 0; kt < 2; kt++) {
        __syncthreads();  // Hl ready (kt=0) / previous compute done (kt=1)
        // load 64x128 W tile (2048 float4s, 8 per thread)
        #pragma unroll
        for (int i = 0; i < 8; i++) {
            int f  = tid + i * 256;    // 0..2047
            int kr = f >> 5;           // 0..63
            int c4 = (f & 31) * 4;
            *(float4*)&Wl[kr * CH + c4] = *(const float4*)&W[(kt * 64 + kr) * CH + c4];
        }
        __syncthreads();
        #pragma unroll 8
        for (int k = 0; k < 64; k++) {
            float hv0 = Hl[r * CH + kt * 64 + k];
            float hv1 = Hl[(r + 8) * CH + kt * 64 + k];
            float4 w  = *(float4*)&Wl[k * CH + cg];
            acc0.x += hv0 * w.x; acc0.y += hv0 * w.y; acc0.z += hv0 * w.z; acc0.w += hv0 * w.w;
            acc1.x += hv1 * w.x; acc1.y += hv1 * w.y; acc1.z += hv1 * w.z; acc1.w += hv1 * w.w;
        }
    }

    int n0 = rowBase + r;
    if (n0 < N_NODES) {
        float s = dis[n0];
        float4 o = make_float4(acc0.x * s, acc0.y * s, acc0.z * s, acc0.w * s);
        *(float4*)&out[n0 * CH + cg] = o;
    }
    int n1 = rowBase + r + 8;
    if (n1 < N_NODES) {
        float s = dis[n1];
        float4 o = make_float4(acc1.x * s, acc1.y * s, acc1.z * s, acc1.w * s);
        *(float4*)&out[n1 * CH + cg] = o;
    }
}

// ---------------- Aggregate: hnext[n] = relu(dis[n]*(sum_e hs[src_e] + hs[n]) + b) ----------------
// one wave per node, lane = 2 channels
__global__ __launch_bounds__(256) void agg_k(const float* __restrict__ hs,
                                             const int* __restrict__ offsets,
                                             const int* __restrict__ csr,
                                             const float* __restrict__ dis,
                                             const float* __restrict__ bias,
                                             float* __restrict__ out) {
    const int wid  = threadIdx.x >> 6;
    const int lane = threadIdx.x & 63;
    const int n = blockIdx.x * 4 + wid;
    if (n >= N_NODES) return;
    const int c = lane * 2;
    float2 acc = *(const float2*)&hs[n * CH + c];   // self-loop term
    const int beg = offsets[n];
    const int end = offsets[n + 1];
    for (int e = beg; e < end; e++) {
        int s = csr[e];
        float2 v = *(const float2*)&hs[s * CH + c];
        acc.x += v.x;
        acc.y += v.y;
    }
    const float dn = dis[n];
    float2 b = *(const float2*)&bias[c];
    float2 r;
    r.x = fmaxf(dn * acc.x + b.x, 0.f);
    r.y = fmaxf(dn * acc.y + b.y, 0.f);
    *(float2*)&out[n * CH + c] = r;
}

// ---------------- Global mean pool (batch sorted) ----------------
__global__ __launch_bounds__(256) void pool_k(const float* __restrict__ h,
                                              const int* __restrict__ batch,
                                              float* __restrict__ gsum,
                                              float* __restrict__ gcnt) {
    const int c    = threadIdx.x & 127;
    const int half = threadIdx.x >> 7;
    const int n0   = blockIdx.x * 256 + half * 128;
    float acc = 0.f;
    float cntAcc = 0.f;
    int curg = -1;
    for (int i = 0; i < 128; i++) {
        int n = n0 + i;
        if (n >= N_NODES) break;
        int g = batch[n];
        if (g != curg) {
            if (curg >= 0) {
                atomicAdd(&gsum[curg * CH + c], acc);
                if (c == 0) atomicAdd(&gcnt[curg], cntAcc);
            }
            acc = 0.f; cntAcc = 0.f; curg = g;
        }
        acc += h[n * CH + c];
        cntAcc += 1.f;
    }
    if (curg >= 0) {
        atomicAdd(&gsum[curg * CH + c], acc);
        if (c == 0) atomicAdd(&gcnt[curg], cntAcc);
    }
}

// ---------------- Head: out[g,o] = (gsum[g]/cnt[g]) @ Wlin + blin ----------------
__global__ __launch_bounds__(128) void head_k(const float* __restrict__ gsum,
                                              const float* __restrict__ gcnt,
                                              const float* __restrict__ Wlin,
                                              const float* __restrict__ blin,
                                              float* __restrict__ out) {
    const int t = threadIdx.x;      // 0..127
    const int g = t >> 1;
    const int o = t & 1;
    float cnt = fmaxf(gcnt[g], 1.f);
    float s = 0.f;
    for (int ci = 0; ci < CH; ci++) s += gsum[g * CH + ci] * Wlin[ci * OUTC + o];
    out[g * OUTC + o] = s / cnt + blin[o];
}

// ---------------- launch ----------------

static inline size_t alignup(size_t x) { return (x + 255) & ~(size_t)255; }

extern "C" void kernel_launch(void* const* d_in, const int* in_sizes, int n_in,
                              void* d_out, int out_size, void* d_ws, size_t ws_size,
                              hipStream_t stream) {
    const float* x     = (const float*)d_in[0];
    const int*   eidx  = (const int*)d_in[1];
    const int*   batch = (const int*)d_in[2];
    const float* W0    = (const float*)d_in[3];
    const float* b0    = (const float*)d_in[4];
    const float* W1    = (const float*)d_in[5];
    const float* b1    = (const float*)d_in[6];
    const float* W2    = (const float*)d_in[7];
    const float* b2    = (const float*)d_in[8];
    const float* Wlin  = (const float*)d_in[9];
    const float* blin  = (const float*)d_in[10];
    float* out = (float*)d_out;

    const int* src = eidx;
    const int* dst = eidx + N_EDGES;

    char* p = (char*)d_ws;
    int*   cnt     = (int*)p;    p += alignup(N_NODES * 4);
    int*   offsets = (int*)p;    p += alignup((N_NODES + 1) * 4);
    int*   cursor  = (int*)p;    p += alignup(N_NODES * 4);
    float* dis     = (float*)p;  p += alignup(N_NODES * 4);
    int*   csr     = (int*)p;    p += alignup((size_t)N_EDGES * 4);
    float* bufA    = (float*)p;  p += alignup((size_t)N_NODES * CH * 4);
    float* bufB    = (float*)p;  p += alignup((size_t)N_NODES * CH * 4);
    float* gsum    = (float*)p;  p += alignup(NGRAPHS * CH * 4);
    float* gcnt    = (float*)p;  p += alignup(NGRAPHS * 4);

    hipMemsetAsync(cnt, 0, N_NODES * 4, stream);
    hipMemsetAsync(gsum, 0, NGRAPHS * CH * 4, stream);
    hipMemsetAsync(gcnt, 0, NGRAPHS * 4, stream);

    const int EB = (N_EDGES + 255) / 256;
    count_k<<<EB, 256, 0, stream>>>(dst, cnt);
    scan_k<<<1, 1024, 0, stream>>>(cnt, offsets, cursor, dis);
    fill_k<<<EB, 256, 0, stream>>>(src, dst, cursor, csr);

    const int GB = (N_NODES + 15) / 16;     // gemm blocks
    const int AB = (N_NODES + 3) / 4;       // agg blocks

    // layer 0: x -> bufB -> bufA
    gemm_scale_k<<<GB, 256, 0, stream>>>(x, W0, dis, bufB);
    agg_k<<<AB, 256, 0, stream>>>(bufB, offsets, csr, dis, b0, bufA);
    // layer 1
    gemm_scale_k<<<GB, 256, 0, stream>>>(bufA, W1, dis, bufB);
    agg_k<<<AB, 256, 0, stream>>>(bufB, offsets, csr, dis, b1, bufA);
    // layer 2
    gemm_scale_k<<<GB, 256, 0, stream>>>(bufA, W2, dis, bufB);
    agg_k<<<AB, 256, 0, stream>>>(bufB, offsets, csr, dis, b2, bufA);

    const int PB = (N_NODES + 255) / 256;
    pool_k<<<PB, 256, 0, stream>>>(bufA, batch, gsum, gcnt);
    head_k<<<1, 128, 0, stream>>>(gsum, gcnt, Wlin, blin, out);
}

// Round 2
// 739.264 us; speedup vs baseline: 1.2063x; 1.2063x over previous
//
#include <hip/hip_runtime.h>

#define N_NODES   50000
#define N_EDGES   1600000
#define CH        128
#define OUTC      2
#define NGRAPHS   64

// ---------------- CSR build ----------------

__global__ void count_k(const int* __restrict__ dst, int* __restrict__ cnt) {
    int e = blockIdx.x * 256 + threadIdx.x;
    if (e < N_EDGES) atomicAdd(&cnt[dst[e]], 1);
}

// single-block exclusive scan over cnt[N_NODES]; also dis = rsqrt(cnt+1), cursor = offsets
__global__ __launch_bounds__(1024) void scan_k(const int* __restrict__ cnt,
                                               int* __restrict__ offsets,
                                               int* __restrict__ cursor,
                                               float* __restrict__ dis) {
    __shared__ int wsum[16];
    __shared__ int wpre[16];
    __shared__ int btot;
    const int tid  = threadIdx.x;
    const int lane = tid & 63;
    const int wid  = tid >> 6;
    int running = 0;
    for (int base = 0; base < N_NODES; base += 1024) {
        int i = base + tid;
        int c = (i < N_NODES) ? cnt[i] : 0;
        int v = c;
        #pragma unroll
        for (int d = 1; d < 64; d <<= 1) {
            int o = __shfl_up(v, d, 64);
            if (lane >= d) v += o;
        }
        if (lane == 63) wsum[wid] = v;
        __syncthreads();
        if (tid < 16) {
            int s  = wsum[tid];
            int sv = s;
            #pragma unroll
            for (int d = 1; d < 16; d <<= 1) {
                int o = __shfl_up(sv, d, 16);
                if (tid >= d) sv += o;
            }
            wpre[tid] = sv - s;          // exclusive prefix of wave sums
            if (tid == 15) btot = sv;    // chunk total
        }
        __syncthreads();
        int excl = v - c + wpre[wid] + running;
        if (i < N_NODES) {
            offsets[i] = excl;
            cursor[i]  = excl;
            dis[i]     = rsqrtf((float)(c + 1));
        }
        running += btot;
        __syncthreads();   // protect wsum/btot before next chunk
    }
    if (tid == 0) offsets[N_NODES] = running;
}

__global__ void fill_k(const int* __restrict__ src, const int* __restrict__ dst,
                       int* __restrict__ cursor, int* __restrict__ csr) {
    int e = blockIdx.x * 256 + threadIdx.x;
    if (e < N_EDGES) {
        int d = dst[e];
        int pos = atomicAdd(&cursor[d], 1);
        csr[pos] = src[e];
    }
}

// ---------------- GEMM:  out = (h @ W) * dis[row]  ----------------
// 16 rows per block, 256 threads, thread computes 2 rows x 4 cols.
__global__ __launch_bounds__(256) void gemm_scale_k(const float* __restrict__ h,
                                                    const float* __restrict__ W,
                                                    const float* __restrict__ dis,
                                                    float* __restrict__ out) {
    __shared__ float Hl[16 * CH];   // 8 KB
    __shared__ float Wl[64 * CH];   // 32 KB
    const int tid = threadIdx.x;
    const int rowBase = blockIdx.x * 16;

    // load 16 rows of h (512 float4s, 2 per thread)
    #pragma unroll
    for (int i = 0; i < 2; i++) {
        int f   = tid + i * 256;       // 0..511
        int r   = f >> 5;              // 0..15
        int c4  = (f & 31) * 4;
        int n   = rowBase + r;
        float4 v = make_float4(0.f, 0.f, 0.f, 0.f);
        if (n < N_NODES) v = *(const float4*)&h[n * CH + c4];
        *(float4*)&Hl[r * CH + c4] = v;
    }

    const int r  = tid >> 5;          // 0..7  (rows r and r+8)
    const int cg = (tid & 31) * 4;    // col group
    float4 acc0 = make_float4(0.f, 0.f, 0.f, 0.f);
    float4 acc1 = make_float4(0.f, 0.f, 0.f, 0.f);

    for (int kt = 0; kt < 2; kt++) {
        __syncthreads();  // Hl ready (kt=0) / previous compute done (kt=1)
        // load 64x128 W tile (2048 float4s, 8 per thread)
        #pragma unroll
        for (int i = 0; i < 8; i++) {
            int f  = tid + i * 256;    // 0..2047
            int kr = f >> 5;           // 0..63
            int c4 = (f & 31) * 4;
            *(float4*)&Wl[kr * CH + c4] = *(const float4*)&W[(kt * 64 + kr) * CH + c4];
        }
        __syncthreads();
        #pragma unroll 8
        for (int k = 0; k < 64; k++) {
            float hv0 = Hl[r * CH + kt * 64 + k];
            float hv1 = Hl[(r + 8) * CH + kt * 64 + k];
            float4 w  = *(float4*)&Wl[k * CH + cg];
            acc0.x += hv0 * w.x; acc0.y += hv0 * w.y; acc0.z += hv0 * w.z; acc0.w += hv0 * w.w;
            acc1.x += hv1 * w.x; acc1.y += hv1 * w.y; acc1.z += hv1 * w.z; acc1.w += hv1 * w.w;
        }
    }

    int n0 = rowBase + r;
    if (n0 < N_NODES) {
        float s = dis[n0];
        float4 o = make_float4(acc0.x * s, acc0.y * s, acc0.z * s, acc0.w * s);
        *(float4*)&out[n0 * CH + cg] = o;
    }
    int n1 = rowBase + r + 8;
    if (n1 < N_NODES) {
        float s = dis[n1];
        float4 o = make_float4(acc1.x * s, acc1.y * s, acc1.z * s, acc1.w * s);
        *(float4*)&out[n1 * CH + cg] = o;
    }
}

// ---------------- Aggregate: hnext[n] = relu(dis[n]*(sum_e hs[src_e] + hs[n]) + b) ----------------
// one wave per node, lane = 2 channels; 8-deep MLP unroll over edges
__global__ __launch_bounds__(256) void agg_k(const float* __restrict__ hs,
                                             const int* __restrict__ offsets,
                                             const int* __restrict__ csr,
                                             const float* __restrict__ dis,
                                             const float* __restrict__ bias,
                                             float* __restrict__ out) {
    const int wid  = threadIdx.x >> 6;
    const int lane = threadIdx.x & 63;
    const int n = blockIdx.x * 4 + wid;
    if (n >= N_NODES) return;
    const int c = lane * 2;

    float ax[8], ay[8];
    #pragma unroll
    for (int j = 0; j < 8; j++) { ax[j] = 0.f; ay[j] = 0.f; }

    // self-loop term
    {
        float2 v = *(const float2*)&hs[(size_t)n * CH + c];
        ax[0] = v.x; ay[0] = v.y;
    }

    const int beg = offsets[n];
    const int end = offsets[n + 1];
    int e = beg;
    for (; e + 8 <= end; e += 8) {
        int idx[8];
        #pragma unroll
        for (int j = 0; j < 8; j++) idx[j] = csr[e + j];
        #pragma unroll
        for (int j = 0; j < 8; j++) {
            float2 v = *(const float2*)&hs[(size_t)idx[j] * CH + c];
            ax[j] += v.x; ay[j] += v.y;
        }
    }
    // tail (<= 7 edges)
    for (; e < end; e++) {
        int s = csr[e];
        float2 v = *(const float2*)&hs[(size_t)s * CH + c];
        ax[0] += v.x; ay[0] += v.y;
    }

    // pairwise combine
    #pragma unroll
    for (int j = 0; j < 4; j++) { ax[j] += ax[j + 4]; ay[j] += ay[j + 4]; }
    #pragma unroll
    for (int j = 0; j < 2; j++) { ax[j] += ax[j + 2]; ay[j] += ay[j + 2]; }
    float sx = ax[0] + ax[1];
    float sy = ay[0] + ay[1];

    const float dn = dis[n];
    float2 b = *(const float2*)&bias[c];
    float2 r;
    r.x = fmaxf(dn * sx + b.x, 0.f);
    r.y = fmaxf(dn * sy + b.y, 0.f);
    *(float2*)&out[n * CH + c] = r;
}

// ---------------- Global mean pool (batch sorted) ----------------
__global__ __launch_bounds__(256) void pool_k(const float* __restrict__ h,
                                              const int* __restrict__ batch,
                                              float* __restrict__ gsum,
                                              float* __restrict__ gcnt) {
    const int c    = threadIdx.x & 127;
    const int half = threadIdx.x >> 7;
    const int n0   = blockIdx.x * 256 + half * 128;
    float acc = 0.f;
    float cntAcc = 0.f;
    int curg = -1;
    for (int i = 0; i < 128; i++) {
        int n = n0 + i;
        if (n >= N_NODES) break;
        int g = batch[n];
        if (g != curg) {
            if (curg >= 0) {
                atomicAdd(&gsum[curg * CH + c], acc);
                if (c == 0) atomicAdd(&gcnt[curg], cntAcc);
            }
            acc = 0.f; cntAcc = 0.f; curg = g;
        }
        acc += h[n * CH + c];
        cntAcc += 1.f;
    }
    if (curg >= 0) {
        atomicAdd(&gsum[curg * CH + c], acc);
        if (c == 0) atomicAdd(&gcnt[curg], cntAcc);
    }
}

// ---------------- Head: out[g,o] = (gsum[g]/cnt[g]) @ Wlin + blin ----------------
__global__ __launch_bounds__(128) void head_k(const float* __restrict__ gsum,
                                              const float* __restrict__ gcnt,
                                              const float* __restrict__ Wlin,
                                              const float* __restrict__ blin,
                                              float* __restrict__ out) {
    const int t = threadIdx.x;      // 0..127
    const int g = t >> 1;
    const int o = t & 1;
    float cnt = fmaxf(gcnt[g], 1.f);
    float s = 0.f;
    for (int ci = 0; ci < CH; ci++) s += gsum[g * CH + ci] * Wlin[ci * OUTC + o];
    out[g * OUTC + o] = s / cnt + blin[o];
}

// ---------------- launch ----------------

static inline size_t alignup(size_t x) { return (x + 255) & ~(size_t)255; }

extern "C" void kernel_launch(void* const* d_in, const int* in_sizes, int n_in,
                              void* d_out, int out_size, void* d_ws, size_t ws_size,
                              hipStream_t stream) {
    const float* x     = (const float*)d_in[0];
    const int*   eidx  = (const int*)d_in[1];
    const int*   batch = (const int*)d_in[2];
    const float* W0    = (const float*)d_in[3];
    const float* b0    = (const float*)d_in[4];
    const float* W1    = (const float*)d_in[5];
    const float* b1    = (const float*)d_in[6];
    const float* W2    = (const float*)d_in[7];
    const float* b2    = (const float*)d_in[8];
    const float* Wlin  = (const float*)d_in[9];
    const float* blin  = (const float*)d_in[10];
    float* out = (float*)d_out;

    const int* src = eidx;
    const int* dst = eidx + N_EDGES;

    char* p = (char*)d_ws;
    int*   cnt     = (int*)p;    p += alignup(N_NODES * 4);
    int*   offsets = (int*)p;    p += alignup((N_NODES + 1) * 4);
    int*   cursor  = (int*)p;    p += alignup(N_NODES * 4);
    float* dis     = (float*)p;  p += alignup(N_NODES * 4);
    int*   csr     = (int*)p;    p += alignup((size_t)N_EDGES * 4);
    float* bufA    = (float*)p;  p += alignup((size_t)N_NODES * CH * 4);
    float* bufB    = (float*)p;  p += alignup((size_t)N_NODES * CH * 4);
    float* gsum    = (float*)p;  p += alignup(NGRAPHS * CH * 4);
    float* gcnt    = (float*)p;  p += alignup(NGRAPHS * 4);

    hipMemsetAsync(cnt, 0, N_NODES * 4, stream);
    hipMemsetAsync(gsum, 0, NGRAPHS * CH * 4, stream);
    hipMemsetAsync(gcnt, 0, NGRAPHS * 4, stream);

    const int EB = (N_EDGES + 255) / 256;
    count_k<<<EB, 256, 0, stream>>>(dst, cnt);
    scan_k<<<1, 1024, 0, stream>>>(cnt, offsets, cursor, dis);
    fill_k<<<EB, 256, 0, stream>>>(src, dst, cursor, csr);

    const int GB = (N_NODES + 15) / 16;     // gemm blocks
    const int AB = (N_NODES + 3) / 4;       // agg blocks

    // layer 0: x -> bufB -> bufA
    gemm_scale_k<<<GB, 256, 0, stream>>>(x, W0, dis, bufB);
    agg_k<<<AB, 256, 0, stream>>>(bufB, offsets, csr, dis, b0, bufA);
    // layer 1
    gemm_scale_k<<<GB, 256, 0, stream>>>(bufA, W1, dis, bufB);
    agg_k<<<AB, 256, 0, stream>>>(bufB, offsets, csr, dis, b1, bufA);
    // layer 2
    gemm_scale_k<<<GB, 256, 0, stream>>>(bufA, W2, dis, bufB);
    agg_k<<<AB, 256, 0, stream>>>(bufB, offsets, csr, dis, b2, bufA);

    const int PB = (N_NODES + 255) / 256;
    pool_k<<<PB, 256, 0, stream>>>(bufA, batch, gsum, gcnt);
    head_k<<<1, 128, 0, stream>>>(gsum, gcnt, Wlin, blin, out);
}

// Round 3
// 643.532 us; speedup vs baseline: 1.3858x; 1.1488x over previous
//
#include <hip/hip_runtime.h>

#define N_NODES   50000
#define N_EDGES   1600000
#define CH        128
#define OUTC      2
#define NGRAPHS   64

#define NBUCK     391          // ceil(N_NODES / 128)
#define EPB       4096         // edges per F1 block
#define F1BLOCKS  391          // ceil(N_EDGES / EPB)
#define BCAP      5120         // max bucket size handled in LDS (mean 4096, sigma ~64)

// ---------------- CSR build ----------------

__global__ void count_k(const int* __restrict__ dst, int* __restrict__ cnt) {
    int e = blockIdx.x * 256 + threadIdx.x;
    if (e < N_EDGES) atomicAdd(&cnt[dst[e]], 1);
}

// single-block exclusive scan over cnt[N_NODES]; also dis = rsqrt(cnt+1), cursor = offsets
__global__ __launch_bounds__(1024) void scan_k(const int* __restrict__ cnt,
                                               int* __restrict__ offsets,
                                               int* __restrict__ cursor,
                                               float* __restrict__ dis) {
    __shared__ int wsum[16];
    __shared__ int wpre[16];
    __shared__ int btot;
    const int tid  = threadIdx.x;
    const int lane = tid & 63;
    const int wid  = tid >> 6;
    int running = 0;
    for (int base = 0; base < N_NODES; base += 1024) {
        int i = base + tid;
        int c = (i < N_NODES) ? cnt[i] : 0;
        int v = c;
        #pragma unroll
        for (int d = 1; d < 64; d <<= 1) {
            int o = __shfl_up(v, d, 64);
            if (lane >= d) v += o;
        }
        if (lane == 63) wsum[wid] = v;
        __syncthreads();
        if (tid < 16) {
            int s  = wsum[tid];
            int sv = s;
            #pragma unroll
            for (int d = 1; d < 16; d <<= 1) {
                int o = __shfl_up(sv, d, 16);
                if (tid >= d) sv += o;
            }
            wpre[tid] = sv - s;          // exclusive prefix of wave sums
            if (tid == 15) btot = sv;    // chunk total
        }
        __syncthreads();
        int excl = v - c + wpre[wid] + running;
        if (i < N_NODES) {
            offsets[i] = excl;
            cursor[i]  = excl;
            dis[i]     = rsqrtf((float)(c + 1));
        }
        running += btot;
        __syncthreads();   // protect wsum/btot before next chunk
    }
    if (tid == 0) offsets[N_NODES] = running;
}

// bucketCursor[b] = offsets[b*128]
__global__ __launch_bounds__(512) void bucket_init_k(const int* __restrict__ offsets,
                                                     int* __restrict__ bucketCursor) {
    int b = threadIdx.x;
    if (b < NBUCK) bucketCursor[b] = offsets[b << 7];
}

// F1: block-local histogram over dst-buckets, reserve staging space, scatter (src,dst) pairs
__global__ __launch_bounds__(256) void bucket_scatter_k(const int* __restrict__ src,
                                                        const int* __restrict__ dst,
                                                        int* __restrict__ bucketCursor,
                                                        int2* __restrict__ stage) {
    __shared__ int hist[NBUCK];
    __shared__ int cur[NBUCK];
    __shared__ int gbase[NBUCK];
    const int tid = threadIdx.x;
    const int e0  = blockIdx.x * EPB;
    const int nE  = min(EPB, N_EDGES - e0);

    for (int i = tid; i < NBUCK; i += 256) hist[i] = 0;
    __syncthreads();
    for (int i = tid; i < nE; i += 256) {
        int d = dst[e0 + i];
        atomicAdd(&hist[d >> 7], 1);
    }
    __syncthreads();
    for (int i = tid; i < NBUCK; i += 256) {
        int h = hist[i];
        gbase[i] = h ? atomicAdd(&bucketCursor[i], h) : 0;
        cur[i] = 0;
    }
    __syncthreads();
    for (int i = tid; i < nE; i += 256) {
        int d = dst[e0 + i];
        int s = src[e0 + i];
        int b = d >> 7;
        int pos = gbase[b] + atomicAdd(&cur[b], 1);
        stage[pos] = make_int2(s, d);
    }
}

// F2: per-bucket ordered fill via LDS, coalesced stream-out
__global__ __launch_bounds__(256) void bucket_fill_k(const int2* __restrict__ stage,
                                                     const int* __restrict__ offsets,
                                                     int* __restrict__ cursor,
                                                     int* __restrict__ csr) {
    __shared__ int lcur[128];
    __shared__ int loc[BCAP];
    const int tid    = threadIdx.x;
    const int first  = blockIdx.x << 7;
    const int nNodes = min(128, N_NODES - first);
    const int base   = offsets[first];
    const int bend   = offsets[first + nNodes];
    const int bsize  = bend - base;

    for (int i = tid; i < nNodes; i += 256) lcur[i] = offsets[first + i] - base;
    __syncthreads();

    if (bsize <= BCAP) {
        for (int i = tid; i < bsize; i += 256) {
            int2 sd = stage[base + i];
            int pos = atomicAdd(&lcur[sd.y - first], 1);
            loc[pos] = sd.x;
        }
        __syncthreads();
        for (int i = tid; i < bsize; i += 256) csr[base + i] = loc[i];
    } else {
        // statistically unreachable fallback: direct global scatter
        for (int i = tid; i < bsize; i += 256) {
            int2 sd = stage[base + i];
            int pos = atomicAdd(&cursor[sd.y], 1);
            csr[pos] = sd.x;
        }
    }
}

// ---------------- GEMM:  out = (h @ W) * dis[row]  ----------------
// 16 rows per block, 256 threads, thread computes 2 rows x 4 cols.
__global__ __launch_bounds__(256) void gemm_scale_k(const float* __restrict__ h,
                                                    const float* __restrict__ W,
                                                    const float* __restrict__ dis,
                                                    float* __restrict__ out) {
    __shared__ float Hl[16 * CH];   // 8 KB
    __shared__ float Wl[64 * CH];   // 32 KB
    const int tid = threadIdx.x;
    const int rowBase = blockIdx.x * 16;

    // load 16 rows of h (512 float4s, 2 per thread)
    #pragma unroll
    for (int i = 0; i < 2; i++) {
        int f   = tid + i * 256;       // 0..511
        int r   = f >> 5;              // 0..15
        int c4  = (f & 31) * 4;
        int n   = rowBase + r;
        float4 v = make_float4(0.f, 0.f, 0.f, 0.f);
        if (n < N_NODES) v = *(const float4*)&h[n * CH + c4];
        *(float4*)&Hl[r * CH + c4] = v;
    }

    const int r  = tid >> 5;          // 0..7  (rows r and r+8)
    const int cg = (tid & 31) * 4;    // col group
    float4 acc0 = make_float4(0.f, 0.f, 0.f, 0.f);
    float4 acc1 = make_float4(0.f, 0.f, 0.f, 0.f);

    for (int kt = 0; kt < 2; kt++) {
        __syncthreads();  // Hl ready (kt=0) / previous compute done (kt=1)
        // load 64x128 W tile (2048 float4s, 8 per thread)
        #pragma unroll
        for (int i = 0; i < 8; i++) {
            int f  = tid + i * 256;    // 0..2047
            int kr = f >> 5;           // 0..63
            int c4 = (f & 31) * 4;
            *(float4*)&Wl[kr * CH + c4] = *(const float4*)&W[(kt * 64 + kr) * CH + c4];
        }
        __syncthreads();
        #pragma unroll 8
        for (int k = 0; k < 64; k++) {
            float hv0 = Hl[r * CH + kt * 64 + k];
            float hv1 = Hl[(r + 8) * CH + kt * 64 + k];
            float4 w  = *(float4*)&Wl[k * CH + cg];
            acc0.x += hv0 * w.x; acc0.y += hv0 * w.y; acc0.z += hv0 * w.z; acc0.w += hv0 * w.w;
            acc1.x += hv1 * w.x; acc1.y += hv1 * w.y; acc1.z += hv1 * w.z; acc1.w += hv1 * w.w;
        }
    }

    int n0 = rowBase + r;
    if (n0 < N_NODES) {
        float s = dis[n0];
        float4 o = make_float4(acc0.x * s, acc0.y * s, acc0.z * s, acc0.w * s);
        *(float4*)&out[n0 * CH + cg] = o;
    }
    int n1 = rowBase + r + 8;
    if (n1 < N_NODES) {
        float s = dis[n1];
        float4 o = make_float4(acc1.x * s, acc1.y * s, acc1.z * s, acc1.w * s);
        *(float4*)&out[n1 * CH + cg] = o;
    }
}

// ---------------- Aggregate: hnext[n] = relu(dis[n]*(sum_e hs[src_e] + hs[n]) + b) ----------------
// one wave per node, lane = 2 channels; 8-deep MLP unroll over edges
__global__ __launch_bounds__(256) void agg_k(const float* __restrict__ hs,
                                             const int* __restrict__ offsets,
                                             const int* __restrict__ csr,
                                             const float* __restrict__ dis,
                                             const float* __restrict__ bias,
                                             float* __restrict__ out) {
    const int wid  = threadIdx.x >> 6;
    const int lane = threadIdx.x & 63;
    const int n = blockIdx.x * 4 + wid;
    if (n >= N_NODES) return;
    const int c = lane * 2;

    float ax[8], ay[8];
    #pragma unroll
    for (int j = 0; j < 8; j++) { ax[j] = 0.f; ay[j] = 0.f; }

    // self-loop term
    {
        float2 v = *(const float2*)&hs[(size_t)n * CH + c];
        ax[0] = v.x; ay[0] = v.y;
    }

    const int beg = offsets[n];
    const int end = offsets[n + 1];
    int e = beg;
    for (; e + 8 <= end; e += 8) {
        int idx[8];
        #pragma unroll
        for (int j = 0; j < 8; j++) idx[j] = csr[e + j];
        #pragma unroll
        for (int j = 0; j < 8; j++) {
            float2 v = *(const float2*)&hs[(size_t)idx[j] * CH + c];
            ax[j] += v.x; ay[j] += v.y;
        }
    }
    // tail (<= 7 edges)
    for (; e < end; e++) {
        int s = csr[e];
        float2 v = *(const float2*)&hs[(size_t)s * CH + c];
        ax[0] += v.x; ay[0] += v.y;
    }

    // pairwise combine
    #pragma unroll
    for (int j = 0; j < 4; j++) { ax[j] += ax[j + 4]; ay[j] += ay[j + 4]; }
    #pragma unroll
    for (int j = 0; j < 2; j++) { ax[j] += ax[j + 2]; ay[j] += ay[j + 2]; }
    float sx = ax[0] + ax[1];
    float sy = ay[0] + ay[1];

    const float dn = dis[n];
    float2 b = *(const float2*)&bias[c];
    float2 r;
    r.x = fmaxf(dn * sx + b.x, 0.f);
    r.y = fmaxf(dn * sy + b.y, 0.f);
    *(float2*)&out[n * CH + c] = r;
}

// ---------------- Global mean pool (batch sorted) ----------------
__global__ __launch_bounds__(256) void pool_k(const float* __restrict__ h,
                                              const int* __restrict__ batch,
                                              float* __restrict__ gsum,
                                              float* __restrict__ gcnt) {
    const int c    = threadIdx.x & 127;
    const int half = threadIdx.x >> 7;
    const int n0   = blockIdx.x * 256 + half * 128;
    float acc = 0.f;
    float cntAcc = 0.f;
    int curg = -1;
    for (int i = 0; i < 128; i++) {
        int n = n0 + i;
        if (n >= N_NODES) break;
        int g = batch[n];
        if (g != curg) {
            if (curg >= 0) {
                atomicAdd(&gsum[curg * CH + c], acc);
                if (c == 0) atomicAdd(&gcnt[curg], cntAcc);
            }
            acc = 0.f; cntAcc = 0.f; curg = g;
        }
        acc += h[n * CH + c];
        cntAcc += 1.f;
    }
    if (curg >= 0) {
        atomicAdd(&gsum[curg * CH + c], acc);
        if (c == 0) atomicAdd(&gcnt[curg], cntAcc);
    }
}

// ---------------- Head: out[g,o] = (gsum[g]/cnt[g]) @ Wlin + blin ----------------
__global__ __launch_bounds__(128) void head_k(const float* __restrict__ gsum,
                                              const float* __restrict__ gcnt,
                                              const float* __restrict__ Wlin,
                                              const float* __restrict__ blin,
                                              float* __restrict__ out) {
    const int t = threadIdx.x;      // 0..127
    const int g = t >> 1;
    const int o = t & 1;
    float cnt = fmaxf(gcnt[g], 1.f);
    float s = 0.f;
    for (int ci = 0; ci < CH; ci++) s += gsum[g * CH + ci] * Wlin[ci * OUTC + o];
    out[g * OUTC + o] = s / cnt + blin[o];
}

// ---------------- launch ----------------

static inline size_t alignup(size_t x) { return (x + 255) & ~(size_t)255; }

extern "C" void kernel_launch(void* const* d_in, const int* in_sizes, int n_in,
                              void* d_out, int out_size, void* d_ws, size_t ws_size,
                              hipStream_t stream) {
    const float* x     = (const float*)d_in[0];
    const int*   eidx  = (const int*)d_in[1];
    const int*   batch = (const int*)d_in[2];
    const float* W0    = (const float*)d_in[3];
    const float* b0    = (const float*)d_in[4];
    const float* W1    = (const float*)d_in[5];
    const float* b1    = (const float*)d_in[6];
    const float* W2    = (const float*)d_in[7];
    const float* b2    = (const float*)d_in[8];
    const float* Wlin  = (const float*)d_in[9];
    const float* blin  = (const float*)d_in[10];
    float* out = (float*)d_out;

    const int* src = eidx;
    const int* dst = eidx + N_EDGES;

    char* p = (char*)d_ws;
    int*   cnt     = (int*)p;    p += alignup(N_NODES * 4);
    int*   offsets = (int*)p;    p += alignup((N_NODES + 1) * 4);
    int*   cursor  = (int*)p;    p += alignup(N_NODES * 4);
    float* dis     = (float*)p;  p += alignup(N_NODES * 4);
    int*   bcur    = (int*)p;    p += alignup(NBUCK * 4);
    int*   csr     = (int*)p;    p += alignup((size_t)N_EDGES * 4);
    float* bufA    = (float*)p;  p += alignup((size_t)N_NODES * CH * 4);
    float* bufB    = (float*)p;  p += alignup((size_t)N_NODES * CH * 4);
    float* gsum    = (float*)p;  p += alignup(NGRAPHS * CH * 4);
    float* gcnt    = (float*)p;  p += alignup(NGRAPHS * 4);

    int2* stage = (int2*)bufA;   // 12.8 MB staging, free until gemm0/agg0

    hipMemsetAsync(cnt, 0, N_NODES * 4, stream);
    hipMemsetAsync(gsum, 0, NGRAPHS * CH * 4, stream);
    hipMemsetAsync(gcnt, 0, NGRAPHS * 4, stream);

    const int EB = (N_EDGES + 255) / 256;
    count_k<<<EB, 256, 0, stream>>>(dst, cnt);
    scan_k<<<1, 1024, 0, stream>>>(cnt, offsets, cursor, dis);
    bucket_init_k<<<1, 512, 0, stream>>>(offsets, bcur);
    bucket_scatter_k<<<F1BLOCKS, 256, 0, stream>>>(src, dst, bcur, stage);
    bucket_fill_k<<<NBUCK, 256, 0, stream>>>(stage, offsets, cursor, csr);

    const int GB = (N_NODES + 15) / 16;     // gemm blocks
    const int AB = (N_NODES + 3) / 4;       // agg blocks

    // layer 0: x -> bufB -> bufA
    gemm_scale_k<<<GB, 256, 0, stream>>>(x, W0, dis, bufB);
    agg_k<<<AB, 256, 0, stream>>>(bufB, offsets, csr, dis, b0, bufA);
    // layer 1
    gemm_scale_k<<<GB, 256, 0, stream>>>(bufA, W1, dis, bufB);
    agg_k<<<AB, 256, 0, stream>>>(bufB, offsets, csr, dis, b1, bufA);
    // layer 2
    gemm_scale_k<<<GB, 256, 0, stream>>>(bufA, W2, dis, bufB);
    agg_k<<<AB, 256, 0, stream>>>(bufB, offsets, csr, dis, b2, bufA);

    const int PB = (N_NODES + 255) / 256;
    pool_k<<<PB, 256, 0, stream>>>(bufA, batch, gsum, gcnt);
    head_k<<<1, 128, 0, stream>>>(gsum, gcnt, Wlin, blin, out);
}